// Round 1
// baseline (438.236 us; speedup 1.0000x reference)
//
#include <hip/hip_runtime.h>

typedef unsigned short u16;
typedef __bf16 bf16x8 __attribute__((ext_vector_type(8)));
typedef float f32x4 __attribute__((ext_vector_type(4)));

#define S_LEN 2048
#define BATCH 4
#define DMODEL 4096
#define NQH 4
#define HD 128

__device__ __forceinline__ u16 f2b(float f) {
    union { float f; unsigned u; } a; a.f = f;
    unsigned u = a.u;
    unsigned r = u + 0x7fffu + ((u >> 16) & 1u);
    return (u16)(r >> 16);
}

// ---------- conversions ----------
__global__ __launch_bounds__(256) void conv_x_kernel(const float* __restrict__ x,
                                                     u16* __restrict__ xb) {
    long i = ((long)blockIdx.x * 256 + threadIdx.x) * 4;
    float4 v = *(const float4*)(x + i);
    ushort4 o;
    o.x = f2b(v.x); o.y = f2b(v.y); o.z = f2b(v.z); o.w = f2b(v.w);
    *(ushort4*)(xb + i) = o;
}

// fused wq|wk|wv, transposed to (768 x 4096) row-major = B^T
__global__ __launch_bounds__(256) void pack_wqkv_kernel(const float* __restrict__ wq,
                                                        const float* __restrict__ wk,
                                                        const float* __restrict__ wv,
                                                        u16* __restrict__ W) {
    int idx = blockIdx.x * 256 + threadIdx.x;   // n*4096 + k, total 768*4096
    int n = idx >> 12, k = idx & 4095;
    float v;
    if (n < 512)      v = wq[(size_t)k * 512 + n];
    else if (n < 640) v = wk[(size_t)k * 128 + (n - 512)];
    else              v = wv[(size_t)k * 128 + (n - 640)];
    W[idx] = f2b(v);
}

// wo (512 x 4096) -> woT (4096 x 512) bf16
__global__ __launch_bounds__(256) void pack_wo_kernel(const float* __restrict__ wo,
                                                      u16* __restrict__ W) {
    int idx = blockIdx.x * 256 + threadIdx.x;   // n*512 + k, total 4096*512
    int n = idx >> 9, k = idx & 511;
    W[idx] = f2b(wo[(size_t)k * 4096 + n]);
}

// ---------- GEMM: C(MxN,f32) = A(MxK,bf16) * B^T(NxK,bf16) ----------
// 128x128 tile, BK=32, 4 waves (2x2), each wave 64x64 = 4x4 mfma frags
__global__ __launch_bounds__(256) void gemm_bf16(const u16* __restrict__ A,
                                                 const u16* __restrict__ B,
                                                 float* __restrict__ C,
                                                 int M, int N, int K) {
    // row stride 40 bf16 = 80B = 5 superbanks (odd) -> conflict-minimal b128 access
    __shared__ __align__(16) u16 sA[128 * 40];
    __shared__ __align__(16) u16 sB[128 * 40];
    const int tid = threadIdx.x;
    const int lane = tid & 63, wid = tid >> 6;
    const int wr = wid >> 1, wc = wid & 1;
    const int bm = blockIdx.y, bn = blockIdx.x;
    const int l15 = lane & 15, g = lane >> 4;

    f32x4 acc[4][4] = {};

    for (int kt = 0; kt < K; kt += 32) {
        __syncthreads();
        #pragma unroll
        for (int it = 0; it < 2; ++it) {
            int idx = it * 256 + tid;
            int r = idx >> 2, c = (idx & 3) * 8;
            *(uint4*)&sA[r * 40 + c] = *(const uint4*)&A[(size_t)(bm * 128 + r) * K + kt + c];
            *(uint4*)&sB[r * 40 + c] = *(const uint4*)&B[(size_t)(bn * 128 + r) * K + kt + c];
        }
        __syncthreads();
        bf16x8 af[4], bfr[4];
        #pragma unroll
        for (int m = 0; m < 4; ++m)
            af[m] = *(const bf16x8*)&sA[(wr * 64 + m * 16 + l15) * 40 + g * 8];
        #pragma unroll
        for (int n = 0; n < 4; ++n)
            bfr[n] = *(const bf16x8*)&sB[(wc * 64 + n * 16 + l15) * 40 + g * 8];
        #pragma unroll
        for (int m = 0; m < 4; ++m)
            #pragma unroll
            for (int n = 0; n < 4; ++n)
                acc[m][n] = __builtin_amdgcn_mfma_f32_16x16x32_bf16(af[m], bfr[n], acc[m][n], 0, 0, 0);
    }

    #pragma unroll
    for (int m = 0; m < 4; ++m) {
        int row = bm * 128 + wr * 64 + m * 16 + g * 4;
        #pragma unroll
        for (int n = 0; n < 4; ++n) {
            int col = bn * 128 + wc * 64 + n * 16 + l15;
            #pragma unroll
            for (int r = 0; r < 4; ++r)
                C[(size_t)(row + r) * N + col] = acc[m][n][r];
        }
    }
}

// ---------- RoPE + RMSNorm + scales, QKV(f32, 8192x768) -> Qb/Kb/Vt (bf16) ----------
// one wave per (row, head); heads 0-3 = q, 4 = k, 5 = v
__global__ __launch_bounds__(256) void rope_rms_kernel(const float* __restrict__ QKV,
                                                       const int* __restrict__ positions,
                                                       u16* __restrict__ Qb,
                                                       u16* __restrict__ Kb,
                                                       u16* __restrict__ Vt) {
    const int w = blockIdx.x * 4 + (threadIdx.x >> 6);
    const int lane = threadIdx.x & 63;
    const int row = w / 6, head = w - row * 6;
    const int s = row & (S_LEN - 1), b = row >> 11;

    if (head == 5) {  // V: bf16 convert + transpose to Vt[b][d][s]
        float v0 = QKV[(size_t)row * 768 + 640 + 2 * lane];
        float v1 = QKV[(size_t)row * 768 + 640 + 2 * lane + 1];
        Vt[((size_t)b * 128 + 2 * lane) * S_LEN + s] = f2b(v0);
        Vt[((size_t)b * 128 + 2 * lane + 1) * S_LEN + s] = f2b(v1);
        return;
    }

    float pos = (float)positions[s];
    float ex = (float)(2 * lane) * (1.0f / 128.0f);
    float inv_freq = expf(-ex * 13.122363377404328f);   // ln(500000)
    float ang = pos * inv_freq;
    float c, sn;
    sincosf(ang, &sn, &c);

    float v0 = QKV[(size_t)row * 768 + head * 128 + 2 * lane];
    float v1 = QKV[(size_t)row * 768 + head * 128 + 2 * lane + 1];
    float o0 = v0 * c - v1 * sn;
    float o1 = v0 * sn + v1 * c;

    float ss = o0 * o0 + o1 * o1;
    #pragma unroll
    for (int m = 1; m < 64; m <<= 1) ss += __shfl_xor(ss, m, 64);
    float rms = rsqrtf(ss * (1.0f / 128.0f) + 1e-6f);

    if (head < 4) {
        float ascale = logf(floorf((pos + 1.0f) * (1.0f / 8192.0f)) + 1.0f) * 0.1f + 1.0f;
        float mult = rms * ascale * 0.08838834764831845f;  // fold 1/sqrt(128)
        unsigned pk = (unsigned)f2b(o0 * mult) | ((unsigned)f2b(o1 * mult) << 16);
        *(unsigned*)&Qb[(size_t)row * 512 + head * 128 + 2 * lane] = pk;
    } else {
        unsigned pk = (unsigned)f2b(o0 * rms) | ((unsigned)f2b(o1 * rms) << 16);
        *(unsigned*)&Kb[(size_t)row * 128 + 2 * lane] = pk;
    }
}

// ---------- flash attention (causal, GQA 4:1) ----------
// grid (16, 32): blockIdx.x = b*4+h, blockIdx.y = q-tile of 64 rows; 4 waves x 16 q-rows
__global__ __launch_bounds__(256) void attn_kernel(const u16* __restrict__ Qb,
                                                   const u16* __restrict__ Kb,
                                                   const u16* __restrict__ Vt,
                                                   u16* __restrict__ Ob) {
    __shared__ __align__(16) u16 p_lds[4][16][40];
    const int tid = threadIdx.x;
    const int lane = tid & 63, wid = tid >> 6;
    const int b = blockIdx.x >> 2, h = blockIdx.x & 3;
    const int q0 = blockIdx.y * 64 + wid * 16;
    const int l15 = lane & 15, g = lane >> 4;

    bf16x8 qf[4];
    {
        const u16* qrow = Qb + (size_t)(b * S_LEN + q0 + l15) * 512 + h * 128 + g * 8;
        #pragma unroll
        for (int c = 0; c < 4; ++c) qf[c] = *(const bf16x8*)(qrow + c * 32);
    }
    f32x4 oacc[8] = {};
    float m_r[4], l_r[4];
    #pragma unroll
    for (int r = 0; r < 4; ++r) { m_r[r] = -1e30f; l_r[r] = 0.f; }

    for (int kv0 = 0; kv0 <= q0 + 15; kv0 += 32) {
        f32x4 sf[2] = {};
        #pragma unroll
        for (int t = 0; t < 2; ++t) {
            const u16* krow = Kb + (size_t)(b * S_LEN + kv0 + t * 16 + l15) * 128 + g * 8;
            #pragma unroll
            for (int c = 0; c < 4; ++c) {
                bf16x8 kf = *(const bf16x8*)(krow + c * 32);
                sf[t] = __builtin_amdgcn_mfma_f32_16x16x32_bf16(qf[c], kf, sf[t], 0, 0, 0);
            }
        }
        float p[2][4], tm[4], f_r[4], rs[4];
        #pragma unroll
        for (int r = 0; r < 4; ++r) {
            int qpos = q0 + g * 4 + r;
            int kp = kv0 + l15;
            float s0 = (kp <= qpos) ? sf[0][r] : -1e30f;
            float s1 = (kp + 16 <= qpos) ? sf[1][r] : -1e30f;
            p[0][r] = s0; p[1][r] = s1;
            tm[r] = fmaxf(s0, s1);
        }
        #pragma unroll
        for (int msk = 1; msk < 16; msk <<= 1)
            #pragma unroll
            for (int r = 0; r < 4; ++r) tm[r] = fmaxf(tm[r], __shfl_xor(tm[r], msk, 64));
        #pragma unroll
        for (int r = 0; r < 4; ++r) {
            float mn = fmaxf(m_r[r], tm[r]);
            f_r[r] = __expf(m_r[r] - mn);
            m_r[r] = mn;
            float p0 = __expf(p[0][r] - mn);
            float p1 = __expf(p[1][r] - mn);
            p[0][r] = p0; p[1][r] = p1;
            rs[r] = p0 + p1;
        }
        #pragma unroll
        for (int msk = 1; msk < 16; msk <<= 1)
            #pragma unroll
            for (int r = 0; r < 4; ++r) rs[r] += __shfl_xor(rs[r], msk, 64);
        #pragma unroll
        for (int r = 0; r < 4; ++r) {
            l_r[r] = l_r[r] * f_r[r] + rs[r];
            #pragma unroll
            for (int ht = 0; ht < 8; ++ht) oacc[ht][r] *= f_r[r];
        }
        // reshape P (D-layout) -> A-fragment layout via per-wave LDS tile
        #pragma unroll
        for (int t = 0; t < 2; ++t)
            #pragma unroll
            for (int r = 0; r < 4; ++r)
                p_lds[wid][g * 4 + r][t * 16 + l15] = f2b(p[t][r]);
        bf16x8 pa = *(const bf16x8*)&p_lds[wid][l15][g * 8];
        #pragma unroll
        for (int ht = 0; ht < 8; ++ht) {
            const u16* vrow = Vt + (size_t)(b * 128 + ht * 16 + l15) * S_LEN + kv0 + g * 8;
            bf16x8 vf = *(const bf16x8*)vrow;
            oacc[ht] = __builtin_amdgcn_mfma_f32_16x16x32_bf16(pa, vf, oacc[ht], 0, 0, 0);
        }
    }

    #pragma unroll
    for (int ht = 0; ht < 8; ++ht)
        #pragma unroll
        for (int r = 0; r < 4; ++r) {
            float o = oacc[ht][r] / l_r[r];
            Ob[(size_t)(b * S_LEN + q0 + g * 4 + r) * 512 + h * 128 + ht * 16 + l15] = f2b(o);
        }
}

extern "C" void kernel_launch(void* const* d_in, const int* in_sizes, int n_in,
                              void* d_out, int out_size, void* d_ws, size_t ws_size,
                              hipStream_t stream) {
    const float* x         = (const float*)d_in[0];
    const int*   positions = (const int*)d_in[1];
    const float* wq        = (const float*)d_in[2];
    const float* wk        = (const float*)d_in[3];
    const float* wv        = (const float*)d_in[4];
    const float* wo        = (const float*)d_in[5];
    float* out = (float*)d_out;

    // Xb (bf16 x) lives in d_out's first 67MB (d_out is 134MB, only written by final GEMM)
    u16* Xb = (u16*)d_out;

    char* ws = (char*)d_ws;
    size_t off = 0;
    auto alloc = [&](size_t bytes) { void* p = ws + off; off = (off + bytes + 255) & ~(size_t)255; return p; };
    u16*   Wqkv = (u16*)alloc(768ull * 4096 * 2);
    u16*   WoT  = (u16*)alloc(4096ull * 512 * 2);
    float* QKV  = (float*)alloc(8192ull * 768 * 4);
    u16*   Qb   = (u16*)alloc(8192ull * 512 * 2);
    u16*   Kb   = (u16*)alloc(8192ull * 128 * 2);
    u16*   Vt   = (u16*)alloc(4ull * 128 * 2048 * 2);
    u16*   Ob   = (u16*)alloc(8192ull * 512 * 2);

    conv_x_kernel<<<(8192 * 4096) / (4 * 256), 256, 0, stream>>>(x, Xb);
    pack_wqkv_kernel<<<(768 * 4096) / 256, 256, 0, stream>>>(wq, wk, wv, Wqkv);
    pack_wo_kernel<<<(4096 * 512) / 256, 256, 0, stream>>>(wo, WoT);

    gemm_bf16<<<dim3(768 / 128, 8192 / 128), 256, 0, stream>>>(Xb, Wqkv, QKV, 8192, 768, 4096);

    rope_rms_kernel<<<(8192 * 6) / 4, 256, 0, stream>>>(QKV, positions, Qb, Kb, Vt);

    attn_kernel<<<dim3(16, 32), 256, 0, stream>>>(Qb, Kb, Vt, Ob);

    gemm_bf16<<<dim3(4096 / 128, 8192 / 128), 256, 0, stream>>>(Ob, WoT, out, 8192, 4096, 512);
}